// Round 7
// baseline (431.532 us; speedup 1.0000x reference)
//
#include <hip/hip_runtime.h>
#include <cstddef>
#include <cstdint>

// GMM E-step: N=200000, K=16, D=64, fp32 in/out.
// R7: precompute -> single wave per component, ZERO barriers. Within one
// wave DS ops retire in program order, so cross-lane RAW through LDS is
// safe without s_barrier; R6's 128 barrier-rounds (83us @ 0.59% VALUBusy)
// collapse into one fused 64-round Cholesky+inverse loop with v_readlane
// broadcasts. Estep (MFMA f16 hi/lo, R5/R6-verified) unchanged.

#define GMM_D 64
#define GMM_K 16

typedef _Float16 half8 __attribute__((ext_vector_type(8)));
typedef float f32x4 __attribute__((ext_vector_type(4)));

// ws: WA [16 comps][16 frags][64 lanes][8 f16] = 262144 B, then tv, cc (f32)
#define WA_BYTES (GMM_K * 16 * 64 * 8 * 2)

// ---------------------------------------------------------------------------
// Precompute: one block = ONE WAVE per component. Fused right-looking
// Cholesky + forward-substitution inverse; no __syncthreads in the loop.
// ---------------------------------------------------------------------------
__global__ __launch_bounds__(64) void gmm_precompute_kernel(
    const float* __restrict__ pi, const float* __restrict__ mus,
    const float* __restrict__ covs, _Float16* __restrict__ WA,
    float* __restrict__ tv, float* __restrict__ cc)
{
    const int k = blockIdx.x;
    const int r = threadIdx.x;  // lane owns row r of A and (during inverse) row r of W

    __shared__ float A_[GMM_D][GMM_D + 1];  // Sigma -> L (in place)
    __shared__ float Wv[GMM_D][GMM_D + 1];  // I -> L^{-1}

    // coalesced Sigma load: 1024 float4, 16 per lane
    {
        const float4* src = reinterpret_cast<const float4*>(covs + (size_t)k * 4096);
        #pragma unroll
        for (int rnd = 0; rnd < 16; ++rnd) {
            const int i4 = rnd * 64 + r;
            const float4 v = src[i4];
            const int row = i4 >> 4, col = (i4 & 15) * 4;
            A_[row][col + 0] = v.x; A_[row][col + 1] = v.y;
            A_[row][col + 2] = v.z; A_[row][col + 3] = v.w;
        }
    }
    #pragma unroll
    for (int c = 0; c < GMM_D; ++c) Wv[r][c] = (r == c) ? 1.0f : 0.0f;
    __syncthreads();  // once; single wave so this is nearly free

    float logdiag = 0.0f;  // lane r ends holding log(L_rr)

    #pragma unroll 1
    for (int j = 0; j < GMM_D; ++j) {
        // ---- form column j of L ----
        const float arj = A_[r][j];          // includes all prior-round updates
        const float pivot = __shfl(arj, j);  // register broadcast, no LDS trip
        const float d = sqrtf(pivot);
        const float inv_d = 1.0f / d;
        const float lrj = (r == j) ? d : ((r > j) ? arj * inv_d : 0.0f);
        if (r == j) logdiag = logf(d);

        // ---- rank-1 trailing update: lane r updates A[r][p], p=j+1..r ----
        // p is loop-uniform -> __shfl(lrj,p) is v_readlane (scalar-cheap).
        for (int p = j + 1; p < GMM_D; ++p) {
            const float lpj = __shfl(lrj, p);
            if (p <= r) A_[r][p] -= lrj * lpj;
        }

        // ---- inverse, fused: row j of W finalizes exactly now ----
        // scale: lane c(=r) handles W[j][c], c<=j (cols>j are structurally 0)
        float wjc = Wv[j][r] * inv_d;
        if (r <= j) Wv[j][r] = wjc;
        // eliminate: lane r (r>j) does W[r][c] -= L[r][j]*W[j][c], c=0..j
        for (int c = 0; c <= j; ++c) {
            const float wc = __shfl(wjc, c);  // v_readlane
            if (r > j) Wv[r][c] -= lrj * wc;
        }
    }

    // ---- t = W mu (lane r = row r; mk[j] wave-uniform -> s_load) ----
    {
        const float* mk = mus + k * GMM_D;
        float s0 = 0.f, s1 = 0.f, s2 = 0.f, s3 = 0.f;
        #pragma unroll 4
        for (int j = 0; j < GMM_D; j += 4) {
            s0 += Wv[r][j + 0] * mk[j + 0];
            s1 += Wv[r][j + 1] * mk[j + 1];
            s2 += Wv[r][j + 2] * mk[j + 2];
            s3 += Wv[r][j + 3] * mk[j + 3];
        }
        tv[k * GMM_D + r] = (s0 + s1) + (s2 + s3);
    }

    // ---- swizzle W -> f16 hi/lo A-fragments ----
    // frag f=mt*4+s: lane L elem u = W[mt*16+(L&15)][(s&1)*32+(L>>4)*8+u];
    // s in {0,1}: hi ; {2,3}: lo. 16B/lane stores, coalesced.
    {
        const int lr = r & 15, q = r >> 4;
        #pragma unroll 1
        for (int f = 0; f < 16; ++f) {
            const int mt = f >> 2, s = f & 3;
            const int row = mt * 16 + lr;
            const int db = (s & 1) * 32 + q * 8;
            half8 hv;
            #pragma unroll
            for (int u = 0; u < 8; ++u) {
                const float v = Wv[row][db + u];
                _Float16 h = (_Float16)v;
                if (s >= 2) h = (_Float16)(v - (float)h);
                hv[u] = h;
            }
            *(half8*)(WA + ((size_t)((k * 16 + f) * 64) + r) * 8) = hv;
        }
    }

    // ---- c_k = log pi_k - sum(log L_ii) - 0.5*D*log(2*pi) ----
    {
        float ll = logdiag;
        #pragma unroll
        for (int off = 32; off > 0; off >>= 1) ll += __shfl_down(ll, off);
        if (r == 0)
            cc[k] = logf(pi[k]) - ll - 0.5f * 64.0f * 1.8378770664093453f;
    }
}

// ---------------------------------------------------------------------------
// E-step (unchanged from R6): block = 4 waves, 64 points; wave w owns comps
// 4w..4w+3. Per (comp, ntile): 4 Mtiles x 6 MFMA 16x16x32 f16 (hi*hi + hi*lo
// + lo*hi), C preloaded with -t, maha reduced in-register + 2 shfl_xor.
// ---------------------------------------------------------------------------
__global__ __launch_bounds__(256) void gmm_estep_kernel(
    const float* __restrict__ X, const _Float16* __restrict__ WA,
    const float* __restrict__ tv, const float* __restrict__ cc,
    float* __restrict__ out, int N)
{
    // xs row (per point): [hi 0..63 | lo 0..63 | pad 8] f16 = 136 (272 B)
    __shared__ _Float16 xs[64 * 136];
    __shared__ float lg[64 * 17];

    const int tid = threadIdx.x;

    // ---- stage X -> f16 hi/lo in LDS: thread t: point t/4, dims (t%4)*16.. ----
    {
        const int p = tid >> 2, qq = tid & 3;
        const int np = blockIdx.x * 64 + p;
        if (np < N) {
            const float4* src = reinterpret_cast<const float4*>(X + (size_t)np * GMM_D) + qq * 4;
            float vv[16];
            #pragma unroll
            for (int u = 0; u < 4; ++u) {
                const float4 v = src[u];
                vv[4 * u + 0] = v.x; vv[4 * u + 1] = v.y;
                vv[4 * u + 2] = v.z; vv[4 * u + 3] = v.w;
            }
            half8 h0, h1, l0, l1;
            #pragma unroll
            for (int u = 0; u < 8; ++u) {
                const _Float16 a = (_Float16)vv[u];
                const _Float16 b = (_Float16)vv[u + 8];
                h0[u] = a; l0[u] = (_Float16)(vv[u] - (float)a);
                h1[u] = b; l1[u] = (_Float16)(vv[u + 8] - (float)b);
            }
            _Float16* row = xs + p * 136;
            *(half8*)(row + qq * 16)          = h0;
            *(half8*)(row + qq * 16 + 8)      = h1;
            *(half8*)(row + 64 + qq * 16)     = l0;
            *(half8*)(row + 64 + qq * 16 + 8) = l1;
        }
    }
    __syncthreads();

    const int lane = tid & 63;
    const int wave = __builtin_amdgcn_readfirstlane(tid >> 6);
    const int pt = lane & 15;
    const int q  = lane >> 4;

    #pragma unroll 1
    for (int kk = 0; kk < 4; ++kk) {
        const int k = wave * 4 + kk;  // wave-uniform

        // A fragments: 16 x global_load_dwordx4, coalesced, L2-resident.
        half8 af[4][4];
        const _Float16* wab = WA + (size_t)k * 8192 + lane * 8;
        #pragma unroll
        for (int mt = 0; mt < 4; ++mt)
            #pragma unroll
            for (int s = 0; s < 4; ++s)
                af[mt][s] = *(const half8*)(wab + (mt * 4 + s) * 512);

        // nt-invariant accumulator inits: -t rows for each Mtile
        f32x4 tk4[4];
        #pragma unroll
        for (int mt = 0; mt < 4; ++mt)
            tk4[mt] = *(const f32x4*)(tv + k * 64 + mt * 16 + q * 4);

        #pragma unroll 1
        for (int nt = 0; nt < 4; ++nt) {
            const _Float16* xrow = xs + (nt * 16 + pt) * 136 + q * 8;
            const half8 bh0 = *(const half8*)(xrow);        // hi dims 0..31
            const half8 bh1 = *(const half8*)(xrow + 32);   // hi dims 32..63
            const half8 bl0 = *(const half8*)(xrow + 64);   // lo dims 0..31
            const half8 bl1 = *(const half8*)(xrow + 96);   // lo dims 32..63

            float mahaP = 0.0f;
            #pragma unroll
            for (int mt = 0; mt < 4; ++mt) {
                f32x4 c = -tk4[mt];
                c = __builtin_amdgcn_mfma_f32_16x16x32_f16(af[mt][0], bh0, c, 0, 0, 0);
                c = __builtin_amdgcn_mfma_f32_16x16x32_f16(af[mt][1], bh1, c, 0, 0, 0);
                c = __builtin_amdgcn_mfma_f32_16x16x32_f16(af[mt][0], bl0, c, 0, 0, 0);
                c = __builtin_amdgcn_mfma_f32_16x16x32_f16(af[mt][1], bl1, c, 0, 0, 0);
                c = __builtin_amdgcn_mfma_f32_16x16x32_f16(af[mt][2], bh0, c, 0, 0, 0);
                c = __builtin_amdgcn_mfma_f32_16x16x32_f16(af[mt][3], bh1, c, 0, 0, 0);
                mahaP += c[0] * c[0] + c[1] * c[1] + c[2] * c[2] + c[3] * c[3];
            }
            mahaP += __shfl_xor(mahaP, 16);
            mahaP += __shfl_xor(mahaP, 32);
            if (q == 0 && (blockIdx.x * 64 + nt * 16 + pt) < N)
                lg[(nt * 16 + pt) * 17 + k] = cc[k] - 0.5f * mahaP;
        }
    }
    __syncthreads();

    // softmax: 4 threads/point, one float4 each (contiguous stores)
    {
        const int p = tid >> 2, qq = tid & 3;
        const int np = blockIdx.x * 64 + p;
        if (np < N) {
            const float* row = &lg[p * 17];
            float m = row[0];
            #pragma unroll
            for (int j = 1; j < GMM_K; ++j) m = fmaxf(m, row[j]);
            float e[GMM_K];
            float s = 0.0f;
            #pragma unroll
            for (int j = 0; j < GMM_K; ++j) { e[j] = __expf(row[j] - m); s += e[j]; }
            const float inv = 1.0f / s;
            float4 v;
            v.x = e[qq * 4 + 0] * inv;
            v.y = e[qq * 4 + 1] * inv;
            v.z = e[qq * 4 + 2] * inv;
            v.w = e[qq * 4 + 3] * inv;
            reinterpret_cast<float4*>(out + (size_t)np * GMM_K)[qq] = v;
        }
    }
}

// ---------------------------------------------------------------------------
extern "C" void kernel_launch(void* const* d_in, const int* in_sizes, int n_in,
                              void* d_out, int out_size, void* d_ws, size_t ws_size,
                              hipStream_t stream)
{
    const float* X    = (const float*)d_in[0];
    const float* pi   = (const float*)d_in[1];
    const float* mus  = (const float*)d_in[2];
    const float* covs = (const float*)d_in[3];
    float* out = (float*)d_out;

    const int N = in_sizes[0] / GMM_D;

    _Float16* WA = (_Float16*)d_ws;
    float* tv = (float*)((char*)d_ws + WA_BYTES);
    float* cc = tv + GMM_K * GMM_D;

    gmm_precompute_kernel<<<dim3(GMM_K), dim3(64), 0, stream>>>(pi, mus, covs, WA, tv, cc);

    const int blocks = (N + 63) / 64;  // 200000/64 = 3125 exactly
    gmm_estep_kernel<<<dim3(blocks), dim3(256), 0, stream>>>(X, WA, tv, cc, out, N);
}

// Round 8
// 237.727 us; speedup vs baseline: 1.8152x; 1.8152x over previous
//
#include <hip/hip_runtime.h>
#include <cstddef>
#include <cstdint>

// GMM E-step: N=200000, K=16, D=64, fp32 in/out.
// R8: precompute v3. R7's single-wave no-barrier premise stands (correct),
// but __shfl with runtime lane index = ds_bpermute inside the inner loops
// made a ~200cyc serialized chain per element (291us, VALUBusy 0.17%).
// v3 broadcasts via single-address LDS reads (pipelined, conflict-free) and
// does all row RMWs as float4 ds_*_b128 (stride 68 = 16B-aligned rows, even
// bank-quad spread). Estep byte-identical to R7 (isolate delta; surface its
// counters next round).

#define GMM_D 64
#define GMM_K 16

typedef _Float16 half8 __attribute__((ext_vector_type(8)));
typedef float f32x4 __attribute__((ext_vector_type(4)));

// ws: WA [16 comps][16 frags][64 lanes][8 f16] = 262144 B, then tv, cc (f32)
#define WA_BYTES (GMM_K * 16 * 64 * 8 * 2)

// ---------------------------------------------------------------------------
// Precompute: one block = ONE WAVE per component. Fused right-looking
// Cholesky + forward-substitution inverse; no barriers in the loop (same-wave
// DS ops retire in order). Broadcasts via same-address LDS reads; RMWs in
// float4.
// ---------------------------------------------------------------------------
__global__ __launch_bounds__(64) void gmm_precompute_kernel(
    const float* __restrict__ pi, const float* __restrict__ mus,
    const float* __restrict__ covs, _Float16* __restrict__ WA,
    float* __restrict__ tv, float* __restrict__ cc)
{
    const int k = blockIdx.x;
    const int r = threadIdx.x;  // lane owns row r of A_ and row r of Wv

    __shared__ float A_[GMM_D][68];  // Sigma -> L-trailing (stride 68: rows 16B-aligned)
    __shared__ float Wv[GMM_D][68];  // I -> L^{-1}
    __shared__ float cj[GMM_D];      // column j of L, rewritten each round

    // coalesced Sigma load: 1024 float4, 16 per lane
    {
        const float4* src = reinterpret_cast<const float4*>(covs + (size_t)k * 4096);
        #pragma unroll
        for (int rnd = 0; rnd < 16; ++rnd) {
            const int i4 = rnd * 64 + r;
            const float4 v = src[i4];
            *(float4*)&A_[i4 >> 4][(i4 & 15) * 4] = v;
        }
    }
    // W := I (row r owned by lane r)
    {
        const float4 z = {0.0f, 0.0f, 0.0f, 0.0f};
        #pragma unroll
        for (int c4 = 0; c4 < 16; ++c4) *(float4*)&Wv[r][c4 * 4] = z;
        Wv[r][r] = 1.0f;
    }
    __syncthreads();  // single wave: cheap

    float logdiag = 0.0f;  // lane j ends holding log(L_jj)

    #pragma unroll 1
    for (int j = 0; j < GMM_D; ++j) {
        // ---- column j of L ----
        const float arj = A_[r][j];          // stride-68 col read (8-way, 1/round: ok)
        const float pivot = __shfl(arj, j);  // runtime-uniform idx; 1/round: ok
        const float d = sqrtf(pivot);
        const float inv_d = 1.0f / d;
        const float lrj = (r == j) ? d : ((r > j) ? arj * inv_d : 0.0f);
        if (r == j) logdiag = 0.5f * logf(pivot);
        cj[r] = lrj;                         // stride-1 write, conflict-free

        // ---- rank-1 trailing update, float4 quads. No element predicates:
        // touched columns <= j are already consumed; rows r<j have lrj=0. ----
        {
            const int q0 = (j + 1) >> 2;
            #pragma unroll 4
            for (int p4 = q0; p4 < 16; ++p4) {
                const float4 cv = *(const float4*)&cj[p4 * 4];  // broadcast read
                float4 av = *(float4*)&A_[r][p4 * 4];
                av.x -= lrj * cv.x; av.y -= lrj * cv.y;
                av.z -= lrj * cv.z; av.w -= lrj * cv.w;
                *(float4*)&A_[r][p4 * 4] = av;
            }
        }

        // ---- inverse, fused: scale row j, then eliminate rows r>j.
        // Row j cols > j are exactly 0, so float4 spans need no masks. ----
        Wv[j][r] *= inv_d;                    // lane r handles column r of row j
        const float e = (r > j) ? lrj : 0.0f; // elim coefficient (0 => no-op RMW)
        {
            const int cmax = j >> 2;
            #pragma unroll 4
            for (int c4 = 0; c4 <= cmax; ++c4) {
                const float4 wj = *(const float4*)&Wv[j][c4 * 4];  // broadcast (scaled)
                float4 wv = *(float4*)&Wv[r][c4 * 4];
                wv.x -= e * wj.x; wv.y -= e * wj.y;
                wv.z -= e * wj.z; wv.w -= e * wj.w;
                *(float4*)&Wv[r][c4 * 4] = wv;
            }
        }
    }

    // ---- t = W mu (lane r = row r; upper of W is exactly 0) ----
    {
        const float* mk = mus + k * GMM_D;   // wave-uniform -> s_load
        float s0 = 0.f, s1 = 0.f, s2 = 0.f, s3 = 0.f;
        #pragma unroll 4
        for (int c4 = 0; c4 < 16; ++c4) {
            const float4 wv = *(const float4*)&Wv[r][c4 * 4];
            s0 += wv.x * mk[c4 * 4 + 0];
            s1 += wv.y * mk[c4 * 4 + 1];
            s2 += wv.z * mk[c4 * 4 + 2];
            s3 += wv.w * mk[c4 * 4 + 3];
        }
        tv[k * GMM_D + r] = (s0 + s1) + (s2 + s3);
    }

    // ---- swizzle W -> f16 hi/lo A-fragments ----
    // frag f=mt*4+s: lane L elem u = W[mt*16+(L&15)][(s&1)*32+(L>>4)*8+u];
    // s in {0,1}: hi ; {2,3}: lo. 16B/lane stores, coalesced.
    {
        const int lr = r & 15, q = r >> 4;
        #pragma unroll 1
        for (int f = 0; f < 16; ++f) {
            const int mt = f >> 2, s = f & 3;
            const int row = mt * 16 + lr;
            const int db = (s & 1) * 32 + q * 8;
            const float4 w0 = *(const float4*)&Wv[row][db];
            const float4 w1 = *(const float4*)&Wv[row][db + 4];
            float vv[8] = {w0.x, w0.y, w0.z, w0.w, w1.x, w1.y, w1.z, w1.w};
            half8 hv;
            #pragma unroll
            for (int u = 0; u < 8; ++u) {
                _Float16 h = (_Float16)vv[u];
                if (s >= 2) h = (_Float16)(vv[u] - (float)h);
                hv[u] = h;
            }
            *(half8*)(WA + ((size_t)((k * 16 + f) * 64) + r) * 8) = hv;
        }
    }

    // ---- c_k = log pi_k - sum(log L_ii) - 0.5*D*log(2*pi) ----
    {
        float ll = logdiag;
        #pragma unroll
        for (int off = 32; off > 0; off >>= 1) ll += __shfl_down(ll, off);
        if (r == 0)
            cc[k] = logf(pi[k]) - ll - 0.5f * 64.0f * 1.8378770664093453f;
    }
}

// ---------------------------------------------------------------------------
// E-step (byte-identical to R7): block = 4 waves, 64 points; wave w owns
// comps 4w..4w+3. Per (comp, ntile): 4 Mtiles x 6 MFMA 16x16x32 f16 (hi*hi +
// hi*lo + lo*hi), C preloaded with -t, maha reduced in-register + 2 shfl_xor.
// ---------------------------------------------------------------------------
__global__ __launch_bounds__(256) void gmm_estep_kernel(
    const float* __restrict__ X, const _Float16* __restrict__ WA,
    const float* __restrict__ tv, const float* __restrict__ cc,
    float* __restrict__ out, int N)
{
    // xs row (per point): [hi 0..63 | lo 0..63 | pad 8] f16 = 136 (272 B)
    __shared__ _Float16 xs[64 * 136];
    __shared__ float lg[64 * 17];

    const int tid = threadIdx.x;

    // ---- stage X -> f16 hi/lo in LDS: thread t: point t/4, dims (t%4)*16.. ----
    {
        const int p = tid >> 2, qq = tid & 3;
        const int np = blockIdx.x * 64 + p;
        if (np < N) {
            const float4* src = reinterpret_cast<const float4*>(X + (size_t)np * GMM_D) + qq * 4;
            float vv[16];
            #pragma unroll
            for (int u = 0; u < 4; ++u) {
                const float4 v = src[u];
                vv[4 * u + 0] = v.x; vv[4 * u + 1] = v.y;
                vv[4 * u + 2] = v.z; vv[4 * u + 3] = v.w;
            }
            half8 h0, h1, l0, l1;
            #pragma unroll
            for (int u = 0; u < 8; ++u) {
                const _Float16 a = (_Float16)vv[u];
                const _Float16 b = (_Float16)vv[u + 8];
                h0[u] = a; l0[u] = (_Float16)(vv[u] - (float)a);
                h1[u] = b; l1[u] = (_Float16)(vv[u + 8] - (float)b);
            }
            _Float16* row = xs + p * 136;
            *(half8*)(row + qq * 16)          = h0;
            *(half8*)(row + qq * 16 + 8)      = h1;
            *(half8*)(row + 64 + qq * 16)     = l0;
            *(half8*)(row + 64 + qq * 16 + 8) = l1;
        }
    }
    __syncthreads();

    const int lane = tid & 63;
    const int wave = __builtin_amdgcn_readfirstlane(tid >> 6);
    const int pt = lane & 15;
    const int q  = lane >> 4;

    #pragma unroll 1
    for (int kk = 0; kk < 4; ++kk) {
        const int k = wave * 4 + kk;  // wave-uniform

        // A fragments: 16 x global_load_dwordx4, coalesced, L2-resident.
        half8 af[4][4];
        const _Float16* wab = WA + (size_t)k * 8192 + lane * 8;
        #pragma unroll
        for (int mt = 0; mt < 4; ++mt)
            #pragma unroll
            for (int s = 0; s < 4; ++s)
                af[mt][s] = *(const half8*)(wab + (mt * 4 + s) * 512);

        // nt-invariant accumulator inits: -t rows for each Mtile
        f32x4 tk4[4];
        #pragma unroll
        for (int mt = 0; mt < 4; ++mt)
            tk4[mt] = *(const f32x4*)(tv + k * 64 + mt * 16 + q * 4);

        #pragma unroll 1
        for (int nt = 0; nt < 4; ++nt) {
            const _Float16* xrow = xs + (nt * 16 + pt) * 136 + q * 8;
            const half8 bh0 = *(const half8*)(xrow);        // hi dims 0..31
            const half8 bh1 = *(const half8*)(xrow + 32);   // hi dims 32..63
            const half8 bl0 = *(const half8*)(xrow + 64);   // lo dims 0..31
            const half8 bl1 = *(const half8*)(xrow + 96);   // lo dims 32..63

            float mahaP = 0.0f;
            #pragma unroll
            for (int mt = 0; mt < 4; ++mt) {
                f32x4 c = -tk4[mt];
                c = __builtin_amdgcn_mfma_f32_16x16x32_f16(af[mt][0], bh0, c, 0, 0, 0);
                c = __builtin_amdgcn_mfma_f32_16x16x32_f16(af[mt][1], bh1, c, 0, 0, 0);
                c = __builtin_amdgcn_mfma_f32_16x16x32_f16(af[mt][0], bl0, c, 0, 0, 0);
                c = __builtin_amdgcn_mfma_f32_16x16x32_f16(af[mt][1], bl1, c, 0, 0, 0);
                c = __builtin_amdgcn_mfma_f32_16x16x32_f16(af[mt][2], bh0, c, 0, 0, 0);
                c = __builtin_amdgcn_mfma_f32_16x16x32_f16(af[mt][3], bh1, c, 0, 0, 0);
                mahaP += c[0] * c[0] + c[1] * c[1] + c[2] * c[2] + c[3] * c[3];
            }
            mahaP += __shfl_xor(mahaP, 16);
            mahaP += __shfl_xor(mahaP, 32);
            if (q == 0 && (blockIdx.x * 64 + nt * 16 + pt) < N)
                lg[(nt * 16 + pt) * 17 + k] = cc[k] - 0.5f * mahaP;
        }
    }
    __syncthreads();

    // softmax: 4 threads/point, one float4 each (contiguous stores)
    {
        const int p = tid >> 2, qq = tid & 3;
        const int np = blockIdx.x * 64 + p;
        if (np < N) {
            const float* row = &lg[p * 17];
            float m = row[0];
            #pragma unroll
            for (int j = 1; j < GMM_K; ++j) m = fmaxf(m, row[j]);
            float e[GMM_K];
            float s = 0.0f;
            #pragma unroll
            for (int j = 0; j < GMM_K; ++j) { e[j] = __expf(row[j] - m); s += e[j]; }
            const float inv = 1.0f / s;
            float4 v;
            v.x = e[qq * 4 + 0] * inv;
            v.y = e[qq * 4 + 1] * inv;
            v.z = e[qq * 4 + 2] * inv;
            v.w = e[qq * 4 + 3] * inv;
            reinterpret_cast<float4*>(out + (size_t)np * GMM_K)[qq] = v;
        }
    }
}

// ---------------------------------------------------------------------------
extern "C" void kernel_launch(void* const* d_in, const int* in_sizes, int n_in,
                              void* d_out, int out_size, void* d_ws, size_t ws_size,
                              hipStream_t stream)
{
    const float* X    = (const float*)d_in[0];
    const float* pi   = (const float*)d_in[1];
    const float* mus  = (const float*)d_in[2];
    const float* covs = (const float*)d_in[3];
    float* out = (float*)d_out;

    const int N = in_sizes[0] / GMM_D;

    _Float16* WA = (_Float16*)d_ws;
    float* tv = (float*)((char*)d_ws + WA_BYTES);
    float* cc = tv + GMM_K * GMM_D;

    gmm_precompute_kernel<<<dim3(GMM_K), dim3(64), 0, stream>>>(pi, mus, covs, WA, tv, cc);

    const int blocks = (N + 63) / 64;  // 200000/64 = 3125 exactly
    gmm_estep_kernel<<<dim3(blocks), dim3(256), 0, stream>>>(X, WA, tv, cc, out, N);
}